// Round 1
// baseline (8498.214 us; speedup 1.0000x reference)
//
#include <hip/hip_runtime.h>
#include <stdint.h>

typedef _Float16 f16;
typedef __attribute__((ext_vector_type(8))) _Float16 f16x8;
typedef __attribute__((ext_vector_type(4))) float f32x4;

#define TT 512
#define FF 3
#define HH 128
#define BB 16384
#define BC 64          // batch rows per block
#define PITCH 296      // hcat row pitch in f16 (592B = 16B-aligned, 8-bank spread)
#define NTH 512        // 8 waves

// Bp0: [ks(5)][gate(4)][col(128)][ksub(4)][e(8)]  f16   (K=160: 128 h0 + 4 x + 28 zero)
// Bp1: [ks(8)][gate(4)][col(128)][ksub(4)][e(8)]  f16   (K=256: 128 h0' + 128 h1)
#define NB0 (5*4*128*32)
#define NB1 (8*4*128*32)
#define WS_BP1_OFF  ((size_t)NB0*2)
#define WS_BIAS_OFF ((size_t)(NB0+NB1)*2)

__device__ __forceinline__ float sigf(float x){
  return __builtin_amdgcn_rcpf(1.f + __expf(-x));
}
__device__ __forceinline__ float tanh_f(float x){
  float t = __expf(2.f*x);
  return 1.f - 2.f*__builtin_amdgcn_rcpf(t + 1.f);
}

__global__ void prep_kernel(
    const float* __restrict__ Wih0, const float* __restrict__ Whh0,
    const float* __restrict__ bih0, const float* __restrict__ bhh0,
    const float* __restrict__ Wih1, const float* __restrict__ Whh1,
    const float* __restrict__ bih1, const float* __restrict__ bhh1,
    f16* __restrict__ Bp0, f16* __restrict__ Bp1, float* __restrict__ biasSum)
{
  int idx = blockIdx.x*256 + threadIdx.x;
  if (idx < NB0){
    int e = idx & 7, ksub = (idx>>3)&3, c = (idx>>5)&127, g = (idx>>12)&3, ks = idx>>14;
    int k = ks*32 + ksub*8 + e;          // 0..159
    int gcol = g*128 + c;                // row of W (4H)
    float v = 0.f;
    if (k < 128)      v = Whh0[gcol*128 + k];
    else if (k < 132) v = Wih0[gcol*4 + (k - 128)];  // [data0,data1,data2,delta]
    Bp0[idx] = (f16)v;
  } else if (idx < NB0 + NB1){
    int j = idx - NB0;
    int e = j & 7, ksub = (j>>3)&3, c = (j>>5)&127, g = (j>>12)&3, ks = j>>14;
    int k = ks*32 + ksub*8 + e;          // 0..255
    int gcol = g*128 + c;
    float v = (k < 128) ? Wih1[gcol*128 + k] : Whh1[gcol*128 + (k - 128)];
    Bp1[j] = (f16)v;
  } else if (idx < NB0 + NB1 + 1024){
    int j = idx - (NB0 + NB1);
    int layer = j >> 9, gcol = j & 511;
    biasSum[j] = layer ? (bih1[gcol] + bhh1[gcol]) : (bih0[gcol] + bhh0[gcol]);
  }
}

__global__ __launch_bounds__(NTH, 2) void lstm_kernel(
    const float* __restrict__ data, const float* __restrict__ PnL,
    const f16*  __restrict__ Bp0,  const f16*  __restrict__ Bp1,
    const float* __restrict__ biasSum, const float* __restrict__ fcW,
    const float* __restrict__ fcb, const int* __restrict__ ploc,
    float* __restrict__ out)
{
  // hcat cols: [0,128) h0 | [128,256) h1 | [256,259) data_t | 259 delta | [260,288) zeros
  __shared__ __align__(16) f16 hcat[BC*PITCH];
  __shared__ float fcw_s[HH];

  const int tid = threadIdx.x;
  const int w   = tid >> 6;        // wave 0..7
  const int l   = tid & 63;
  const int l15 = l & 15;
  const int lhi = l >> 4;          // 0..3
  const int jc  = w*16 + l15;      // owned h-column 0..127
  const int bg0 = blockIdx.x * BC;

  for (int i = tid; i < BC*PITCH; i += NTH) hcat[i] = (f16)0.f;
  if (tid < HH) fcw_s[tid] = fcW[tid];

  float bias0[4], bias1[4];
#pragma unroll
  for (int g = 0; g < 4; ++g){
    bias0[g] = biasSum[g*HH + jc];
    bias1[g] = biasSum[512 + g*HH + jc];
  }
  const float fcb0 = fcb[0];
  const int   pl   = ploc[0];

  __syncthreads();
  // stage data for t=0
  if (tid >= 64 && tid < 64+192){
    int idx = tid - 64;
    int r = idx/3, f = idx - 3*r;
    hcat[r*PITCH + 256 + f] = (f16)data[(size_t)(bg0 + r)*TT*FF + f];
  }
  if (tid < BC) out[(size_t)(bg0 + tid)*513] = 0.f;   // delta_his[:,0] = 0

  float c0s[16], c1s[16];
#pragma unroll
  for (int e = 0; e < 16; ++e){ c0s[e] = 0.f; c1s[e] = 0.f; }

  const int row8 = tid >> 3;   // batch row for delta-dot
  const int sub  = tid & 7;
  float pnl = 0.f, dold = 0.f;

  __syncthreads();

  for (int t = 0; t < TT; ++t){
    f32x4 acc[4][4];
    // ================= G0: gates0 = [h0,x] @ W0^T + b =================
#pragma unroll
    for (int g = 0; g < 4; ++g){
      f32x4 v = {bias0[g], bias0[g], bias0[g], bias0[g]};
#pragma unroll
      for (int m = 0; m < 4; ++m) acc[m][g] = v;
    }
#pragma unroll
    for (int ks = 0; ks < 5; ++ks){
      const int colA = (ks < 4 ? ks*32 : 256) + 8*lhi;
      f16x8 a[4];
#pragma unroll
      for (int m = 0; m < 4; ++m)
        a[m] = *(const f16x8*)&hcat[(m*16 + l15)*PITCH + colA];
      f16x8 bfr[4];
      const f16* bp = Bp0 + ks*16384 + jc*32 + lhi*8;
#pragma unroll
      for (int g = 0; g < 4; ++g)
        bfr[g] = *(const f16x8*)(bp + g*4096);
#pragma unroll
      for (int m = 0; m < 4; ++m)
#pragma unroll
        for (int g = 0; g < 4; ++g)
          acc[m][g] = __builtin_amdgcn_mfma_f32_16x16x32_f16(a[m], bfr[g], acc[m][g], 0, 0, 0);
    }
    __syncthreads();   // (1) all reads of h0/x complete

    // ================= cell 0 (register-local) =================
#pragma unroll
    for (int m = 0; m < 4; ++m){
#pragma unroll
      for (int r = 0; r < 4; ++r){
        const int e = m*4 + r;
        float iv = acc[m][0][r], fv = acc[m][1][r];
        float gv = acc[m][2][r], ov = acc[m][3][r];
        float c = sigf(fv)*c0s[e] + sigf(iv)*tanh_f(gv);
        c0s[e] = c;
        float h = sigf(ov)*tanh_f(c);
        hcat[(m*16 + lhi*4 + r)*PITCH + jc] = (f16)h;
      }
    }
    __syncthreads();   // (2) h0' visible

    // ================= G1: gates1 = [h0',h1] @ W1^T + b =================
#pragma unroll
    for (int g = 0; g < 4; ++g){
      f32x4 v = {bias1[g], bias1[g], bias1[g], bias1[g]};
#pragma unroll
      for (int m = 0; m < 4; ++m) acc[m][g] = v;
    }
#pragma unroll
    for (int ks = 0; ks < 8; ++ks){
      const int colA = ks*32 + 8*lhi;
      f16x8 a[4];
#pragma unroll
      for (int m = 0; m < 4; ++m)
        a[m] = *(const f16x8*)&hcat[(m*16 + l15)*PITCH + colA];
      f16x8 bfr[4];
      const f16* bp = Bp1 + ks*16384 + jc*32 + lhi*8;
#pragma unroll
      for (int g = 0; g < 4; ++g)
        bfr[g] = *(const f16x8*)(bp + g*4096);
#pragma unroll
      for (int m = 0; m < 4; ++m)
#pragma unroll
        for (int g = 0; g < 4; ++g)
          acc[m][g] = __builtin_amdgcn_mfma_f32_16x16x32_f16(a[m], bfr[g], acc[m][g], 0, 0, 0);
    }
    __syncthreads();   // (3) all reads of h0'/h1 complete

    // ================= cell 1 =================
#pragma unroll
    for (int m = 0; m < 4; ++m){
#pragma unroll
      for (int r = 0; r < 4; ++r){
        const int e = m*4 + r;
        float iv = acc[m][0][r], fv = acc[m][1][r];
        float gv = acc[m][2][r], ov = acc[m][3][r];
        float c = sigf(fv)*c1s[e] + sigf(iv)*tanh_f(gv);
        c1s[e] = c;
        float h = sigf(ov)*tanh_f(c);
        hcat[(m*16 + lhi*4 + r)*PITCH + 128 + jc] = (f16)h;
      }
    }
    __syncthreads();   // (4) h1' visible

    // ================= delta = h1' @ fcW^T + fcb ; pnl ; restage x =================
    {
      const f16* hp = &hcat[row8*PITCH + 128 + sub*16];
      f16x8 v0 = *(const f16x8*)hp;
      f16x8 v1 = *(const f16x8*)(hp + 8);
      float s = 0.f;
#pragma unroll
      for (int u = 0; u < 8; ++u) s += (float)v0[u] * fcw_s[sub*16 + u];
#pragma unroll
      for (int u = 0; u < 8; ++u) s += (float)v1[u] * fcw_s[sub*16 + 8 + u];
      s += __shfl_xor(s, 1);
      s += __shfl_xor(s, 2);
      s += __shfl_xor(s, 4);
      if (sub == 0){
        const float dnew  = s + fcb0;
        const int   bg    = bg0 + row8;
        const float price = data[(size_t)(bg*TT + t)*FF + pl];
        pnl += (dold - dnew) * price;
        out[(size_t)bg*513 + t + 1] = dnew;
        hcat[row8*PITCH + 259] = (f16)dnew;
        dold = dnew;
        if (t == TT-1){
          const float lastp = data[(size_t)(bg*TT + (TT-1))*FF + 0];
          out[(size_t)BB*513 + bg] = pnl + dnew*lastp + PnL[bg];
        }
      }
      if (t < TT-1 && tid >= 64 && tid < 64+192){
        int idx = tid - 64;
        int r = idx/3, f = idx - 3*r;
        hcat[r*PITCH + 256 + f] = (f16)data[(size_t)((bg0 + r)*TT + (t+1))*FF + f];
      }
    }
    __syncthreads();   // (5) x/delta for t+1 visible
  }
}

extern "C" void kernel_launch(void* const* d_in, const int* in_sizes, int n_in,
                              void* d_out, int out_size, void* d_ws, size_t ws_size,
                              hipStream_t stream)
{
  const float* data = (const float*)d_in[0];
  const float* PnL  = (const float*)d_in[1];
  const float* Wih0 = (const float*)d_in[2];
  const float* Whh0 = (const float*)d_in[3];
  const float* bih0 = (const float*)d_in[4];
  const float* bhh0 = (const float*)d_in[5];
  const float* Wih1 = (const float*)d_in[6];
  const float* Whh1 = (const float*)d_in[7];
  const float* bih1 = (const float*)d_in[8];
  const float* bhh1 = (const float*)d_in[9];
  const float* fcW  = (const float*)d_in[10];
  const float* fcb  = (const float*)d_in[11];
  const int*   ploc = (const int*)d_in[12];

  f16*   Bp0     = (f16*)d_ws;
  f16*   Bp1     = (f16*)((char*)d_ws + WS_BP1_OFF);
  float* biasSum = (float*)((char*)d_ws + WS_BIAS_OFF);
  float* out     = (float*)d_out;

  const int prepN = NB0 + NB1 + 1024;
  prep_kernel<<<(prepN + 255)/256, 256, 0, stream>>>(
      Wih0, Whh0, bih0, bhh0, Wih1, Whh1, bih1, bhh1, Bp0, Bp1, biasSum);
  lstm_kernel<<<BB/BC, NTH, 0, stream>>>(
      data, PnL, Bp0, Bp1, biasSum, fcW, fcb, ploc, out);
}